// Round 1
// baseline (39728.091 us; speedup 1.0000x reference)
//
#include <hip/hip_runtime.h>
#include <cstdint>
#include <cstddef>

#define ZB 512
#define ZT 256
#define ZIN 64
#define ZEH 128
#define ZH 512
#define ZG 2048
#define ZNC 8

typedef __attribute__((ext_vector_type(8))) short s8v;
typedef __attribute__((ext_vector_type(4))) float f4v;
typedef unsigned short u16;
typedef unsigned int u32;

__device__ __forceinline__ u16 f2bf(float f){
  u32 u = __builtin_bit_cast(u32, f);
  u += 0x7FFFu + ((u >> 16) & 1u);
  return (u16)(u >> 16);
}
__device__ __forceinline__ float bf2f(u16 h){
  u32 u = ((u32)h) << 16;
  return __builtin_bit_cast(float, u);
}
__device__ __forceinline__ float sigf(float x){ return 1.f / (1.f + __expf(-x)); }
__device__ __forceinline__ float tanhfast(float x){ return 1.f - 2.f / (1.f + __expf(2.f * x)); }

// ---------------------------------------------------------------------------
// Fold: Wc[2048][128] = W_ih @ W2 (bf16), bc[2048] = W_ih@b2 + b_ih + b_hh
// ---------------------------------------------------------------------------
__global__ __launch_bounds__(128)
void k_fold(const float* __restrict__ W_ih, const float* __restrict__ W2,
            const float* __restrict__ b2, const float* __restrict__ b_ih,
            const float* __restrict__ b_hh, u16* __restrict__ Wc,
            float* __restrict__ bc)
{
  const int r = blockIdx.x, c = threadIdx.x;
  const float* wr = W_ih + (size_t)r * ZH;
  float acc = 0.f;
  for (int k = 0; k < ZH; ++k) acc += wr[k] * W2[(size_t)k * ZEH + c];
  Wc[(size_t)r * ZEH + c] = f2bf(acc);
  __shared__ float red[128];
  float p = 0.f;
  for (int k = c; k < ZH; k += 128) p += wr[k] * b2[k];
  red[c] = p; __syncthreads();
  for (int s = 64; s > 0; s >>= 1){ if (c < s) red[c] += red[c + s]; __syncthreads(); }
  if (c == 0) bc[r] = red[0] + b_ih[r] + b_hh[r];
}

// ---------------------------------------------------------------------------
// Convert W_hh to bf16 [2048][512]
// ---------------------------------------------------------------------------
__global__ __launch_bounds__(256)
void k_cvt(const float* __restrict__ src, u16* __restrict__ dst, int n)
{
  int i = blockIdx.x * 256 + threadIdx.x;
  if (i < n) dst[i] = f2bf(src[i]);
}

// ---------------------------------------------------------------------------
// Encoder layer 1: X1[B*T][128] = bf16(LeakyReLU(seq @ W1^T + b1))
// ---------------------------------------------------------------------------
__global__ __launch_bounds__(256)
void k_enc(const float* __restrict__ seq, const float* __restrict__ W1,
           const float* __restrict__ b1, u16* __restrict__ X1)
{
  __shared__ float w1s[ZEH * 65];
  __shared__ float sqs[64 * 65];
  const int tid = threadIdx.x;
  const size_t rb = (size_t)blockIdx.x * 64;
  for (int i = tid; i < ZEH * ZIN; i += 256){ int r = i >> 6, c = i & 63; w1s[r * 65 + c] = W1[i]; }
  for (int i = tid; i < 64 * ZIN; i += 256){ int r = i >> 6, c = i & 63; sqs[r * 65 + c] = seq[(rb + r) * ZIN + c]; }
  __syncthreads();
  const int cg = tid & 31, rg = tid >> 5;   // 32 col-groups x 4 cols, 8 row-groups x 8 rows
  float acc[8][4];
  #pragma unroll
  for (int i = 0; i < 8; ++i){
    #pragma unroll
    for (int j = 0; j < 4; ++j) acc[i][j] = 0.f;
  }
  for (int k = 0; k < ZIN; ++k){
    float wv[4], sv[8];
    #pragma unroll
    for (int j = 0; j < 4; ++j) wv[j] = w1s[(cg * 4 + j) * 65 + k];
    #pragma unroll
    for (int i = 0; i < 8; ++i) sv[i] = sqs[(rg * 8 + i) * 65 + k];
    #pragma unroll
    for (int i = 0; i < 8; ++i){
      #pragma unroll
      for (int j = 0; j < 4; ++j) acc[i][j] += sv[i] * wv[j];
    }
  }
  #pragma unroll
  for (int i = 0; i < 8; ++i){
    ushort4 pk;
    float v0 = acc[i][0] + b1[cg * 4 + 0]; v0 = v0 > 0.f ? v0 : 0.01f * v0;
    float v1 = acc[i][1] + b1[cg * 4 + 1]; v1 = v1 > 0.f ? v1 : 0.01f * v1;
    float v2 = acc[i][2] + b1[cg * 4 + 2]; v2 = v2 > 0.f ? v2 : 0.01f * v2;
    float v3 = acc[i][3] + b1[cg * 4 + 3]; v3 = v3 > 0.f ? v3 : 0.01f * v3;
    pk.x = f2bf(v0); pk.y = f2bf(v1); pk.z = f2bf(v2); pk.w = f2bf(v3);
    *(ushort4*)(X1 + (rb + rg * 8 + i) * ZEH + cg * 4) = pk;
  }
}

// ---------------------------------------------------------------------------
// G-projection (chunk): Gc[B*Tc][2048] = bf16(X1 @ Wc^T + bc)
// grid = (B*Tc/64) m-blocks * 8 n-blocks
// ---------------------------------------------------------------------------
__global__ __launch_bounds__(256, 2)
void k_gproj(const u16* __restrict__ X1, const u16* __restrict__ Wc,
             const float* __restrict__ bc, u16* __restrict__ Gc,
             int t0, int lgTc)
{
  const int mb = blockIdx.x >> 3, nb = blockIdx.x & 7;
  const int w = threadIdx.x >> 6, l = threadIdx.x & 63;
  const int lr = l & 15, lg = l >> 4;
  const int Tcm = (1 << lgTc) - 1;
  const int m0 = mb * 64;
  const int n0 = nb * 256 + w * 64;

  s8v a[4][4];
  #pragma unroll
  for (int mt = 0; mt < 4; ++mt){
    int cr = m0 + mt * 16 + lr;
    int b = cr >> lgTc, tt = cr & Tcm;
    const u16* xr = X1 + ((size_t)(b * ZT + t0 + tt)) * ZEH;
    #pragma unroll
    for (int kt = 0; kt < 4; ++kt)
      a[mt][kt] = *(const s8v*)(xr + kt * 32 + lg * 8);
  }
  f4v acc[4][4];
  #pragma unroll
  for (int i = 0; i < 4; ++i){
    #pragma unroll
    for (int j = 0; j < 4; ++j){ acc[i][j][0]=0.f; acc[i][j][1]=0.f; acc[i][j][2]=0.f; acc[i][j][3]=0.f; }
  }
  #pragma unroll
  for (int nt = 0; nt < 4; ++nt){
    const u16* wr = Wc + ((size_t)(n0 + nt * 16 + lr)) * ZEH;
    #pragma unroll
    for (int kt = 0; kt < 4; ++kt){
      s8v bfr = *(const s8v*)(wr + kt * 32 + lg * 8);
      #pragma unroll
      for (int mt = 0; mt < 4; ++mt)
        acc[nt][mt] = __builtin_amdgcn_mfma_f32_16x16x32_bf16(a[mt][kt], bfr, acc[nt][mt], 0, 0, 0);
    }
  }
  #pragma unroll
  for (int nt = 0; nt < 4; ++nt){
    int n = n0 + nt * 16 + lr;
    float bias = bc[n];
    #pragma unroll
    for (int mt = 0; mt < 4; ++mt){
      #pragma unroll
      for (int r = 0; r < 4; ++r){
        int row = m0 + mt * 16 + lg * 4 + r;
        Gc[(size_t)row * ZG + n] = f2bf(acc[nt][mt][r] + bias);
      }
    }
  }
}

// ---------------------------------------------------------------------------
// LSTM chunk: 32 wgs x 16 batch rows; per step per wave: [16,512]x[512,512]
// bf16 MFMA into f32, register-local gate fusion. No grid sync (batch-split).
// ---------------------------------------------------------------------------
__global__ __launch_bounds__(256, 1)
void k_lstm(const u16* __restrict__ Gc, const u16* __restrict__ Whh,
            const float* __restrict__ Wfc, const float* __restrict__ bfc,
            float* __restrict__ c_save, u16* __restrict__ h_save,
            float* __restrict__ out, int Tc, int first, int last)
{
  __shared__ u16 Gbuf[2][16 * ZG];   // 128 KiB, double-buffered gate pre-acts
  __shared__ u16 h16[16 * ZH];       // 16 KiB, XOR-swizzled bf16 h
  const int tid = threadIdx.x;
  const int w = tid >> 6, l = tid & 63;
  const int lr = l & 15, lg = l >> 4;
  const int wg = blockIdx.x;
  const int r0 = wg * 16;

  float c_reg[8][4];
  if (first){
    for (int i = tid; i < 16 * ZH; i += 256) h16[i] = 0;
    #pragma unroll
    for (int a = 0; a < 8; ++a){
      #pragma unroll
      for (int b = 0; b < 4; ++b) c_reg[a][b] = 0.f;
    }
  } else {
    for (int i = tid; i < 16 * ZH; i += 256) h16[i] = h_save[wg * (16 * ZH) + i];
    const float* cs = c_save + ((size_t)(wg * 256 + tid)) * 32;
    #pragma unroll
    for (int a = 0; a < 8; ++a){
      #pragma unroll
      for (int b = 0; b < 4; ++b) c_reg[a][b] = cs[a * 4 + b];
    }
  }

  // register-staged async G tile loads (T14 split): thread stages row i, 16B
  s8v stg[16];
  #pragma unroll
  for (int i = 0; i < 16; ++i)
    stg[i] = *(const s8v*)(Gc + ((size_t)((r0 + i) * Tc + 0)) * ZG + tid * 8);
  #pragma unroll
  for (int i = 0; i < 16; ++i){
    int e = i * ZG + tid * 8;
    *(s8v*)(&Gbuf[0][e ^ ((i & 7) << 3)]) = stg[i];
  }
  if (Tc > 1){
    #pragma unroll
    for (int i = 0; i < 16; ++i)
      stg[i] = *(const s8v*)(Gc + ((size_t)((r0 + i) * Tc + 1)) * ZG + tid * 8);
  }
  __syncthreads();

  for (int tt = 0; tt < Tc; ++tt){
    // phase A: commit staged G(tt+1) to LDS, issue loads for G(tt+2)
    if (tt + 1 < Tc){
      u16* gb = Gbuf[(tt + 1) & 1];
      #pragma unroll
      for (int i = 0; i < 16; ++i){
        int e = i * ZG + tid * 8;
        *(s8v*)(&gb[e ^ ((i & 7) << 3)]) = stg[i];
      }
      if (tt + 2 < Tc){
        #pragma unroll
        for (int i = 0; i < 16; ++i)
          stg[i] = *(const s8v*)(Gc + ((size_t)((r0 + i) * Tc + (tt + 2))) * ZG + tid * 8);
      }
    }
    // phase B: preload A-fragments (h) before anyone overwrites h16
    s8v af[16];
    #pragma unroll
    for (int kt = 0; kt < 16; ++kt){
      int e = lr * ZH + kt * 32 + lg * 8;
      af[kt] = *(const s8v*)(&h16[e ^ ((lr & 7) << 3)]);
    }
    __syncthreads();

    const u16* gcur = Gbuf[tt & 1];
    // phase C: 4 chunks of (2 h-col tiles x 4 gates)
    #pragma unroll
    for (int ci = 0; ci < 4; ++ci){
      f4v acc[2][4];
      #pragma unroll
      for (int e2 = 0; e2 < 2; ++e2){
        int ht = (ci * 2 + e2) * 4 + w;
        #pragma unroll
        for (int gt = 0; gt < 4; ++gt){
          int nc = (gt * 32 + ht) * 16 + lr;
          f4v a0;
          #pragma unroll
          for (int r = 0; r < 4; ++r){
            int row = lg * 4 + r;
            int e = row * ZG + nc;
            a0[r] = bf2f(gcur[e ^ ((row & 7) << 3)]);
          }
          acc[e2][gt] = a0;
        }
      }
      const u16* bp[2][4];
      #pragma unroll
      for (int e2 = 0; e2 < 2; ++e2){
        int ht = (ci * 2 + e2) * 4 + w;
        #pragma unroll
        for (int gt = 0; gt < 4; ++gt)
          bp[e2][gt] = Whh + ((size_t)((gt * 32 + ht) * 16 + lr)) * ZH + lg * 8;
      }
      #pragma unroll
      for (int kt = 0; kt < 16; ++kt){
        #pragma unroll
        for (int e2 = 0; e2 < 2; ++e2){
          #pragma unroll
          for (int gt = 0; gt < 4; ++gt){
            s8v bfr = *(const s8v*)(bp[e2][gt] + kt * 32);
            acc[e2][gt] = __builtin_amdgcn_mfma_f32_16x16x32_bf16(af[kt], bfr, acc[e2][gt], 0, 0, 0);
          }
        }
      }
      #pragma unroll
      for (int e2 = 0; e2 < 2; ++e2){
        int ht = (ci * 2 + e2) * 4 + w;
        #pragma unroll
        for (int r = 0; r < 4; ++r){
          float iv = sigf(acc[e2][0][r]);
          float fv = sigf(acc[e2][1][r]);
          float gv = tanhfast(acc[e2][2][r]);
          float ov = sigf(acc[e2][3][r]);
          float cv = fv * c_reg[ci * 2 + e2][r] + iv * gv;
          c_reg[ci * 2 + e2][r] = cv;
          float hv = ov * tanhfast(cv);
          int row = lg * 4 + r;
          int e = row * ZH + ht * 16 + lr;
          h16[e ^ ((row & 7) << 3)] = f2bf(hv);
        }
      }
    }
    __syncthreads();
  }

  if (!last){
    for (int i = tid; i < 16 * ZH; i += 256) h_save[wg * (16 * ZH) + i] = h16[i];
    float* cs = c_save + ((size_t)(wg * 256 + tid)) * 32;
    #pragma unroll
    for (int a = 0; a < 8; ++a){
      #pragma unroll
      for (int b = 0; b < 4; ++b) cs[a * 4 + b] = c_reg[a][b];
    }
  } else {
    if (tid < 128){
      int m = tid >> 3, c = tid & 7;
      float acc = bfc[c];
      const float* wr = Wfc + (size_t)c * ZH;
      for (int k = 0; k < ZH; ++k){
        int e = m * ZH + k;
        acc += bf2f(h16[e ^ ((m & 7) << 3)]) * wr[k];
      }
      out[(size_t)(r0 + m) * ZNC + c] = acc;
    }
  }
}

// ---------------------------------------------------------------------------
extern "C" void kernel_launch(void* const* d_in, const int* in_sizes, int n_in,
                              void* d_out, int out_size, void* d_ws, size_t ws_size,
                              hipStream_t stream)
{
  const float* seq  = (const float*)d_in[0];
  const float* W1   = (const float*)d_in[1];
  const float* b1   = (const float*)d_in[2];
  const float* W2   = (const float*)d_in[3];
  const float* b2   = (const float*)d_in[4];
  const float* W_ih = (const float*)d_in[5];
  const float* W_hh = (const float*)d_in[6];
  const float* b_ih = (const float*)d_in[7];
  const float* b_hh = (const float*)d_in[8];
  const float* Wfc  = (const float*)d_in[9];
  const float* bfc  = (const float*)d_in[10];
  float* out = (float*)d_out;

  char* ws = (char*)d_ws;
  size_t off = 0;
  auto alloc = [&](size_t bytes){ void* p = ws + off; off += (bytes + 255) & ~(size_t)255; return p; };
  u16*   Wc  = (u16*)  alloc((size_t)ZG * ZEH * 2);
  float* bc  = (float*)alloc((size_t)ZG * 4);
  u16*   Whh = (u16*)  alloc((size_t)ZG * ZH * 2);
  u16*   X1  = (u16*)  alloc((size_t)ZB * ZT * ZEH * 2);
  float* csv = (float*)alloc((size_t)ZB * ZH * 4);
  u16*   hsv = (u16*)  alloc((size_t)ZB * ZH * 2);
  size_t fixed = off;
  int Tc = 64;
  while (Tc > 4 && fixed + (size_t)ZB * Tc * ZG * 2 > ws_size) Tc >>= 1;
  u16* Gc = (u16*)alloc((size_t)ZB * Tc * ZG * 2);
  int lgTc = __builtin_ctz((unsigned)Tc);

  hipLaunchKernelGGL(k_fold, dim3(ZG), dim3(128), 0, stream, W_ih, W2, b2, b_ih, b_hh, Wc, bc);
  hipLaunchKernelGGL(k_cvt, dim3((ZG * ZH + 255) / 256), dim3(256), 0, stream, W_hh, Whh, ZG * ZH);
  hipLaunchKernelGGL(k_enc, dim3(ZB * ZT / 64), dim3(256), 0, stream, seq, W1, b1, X1);

  int nch = ZT / Tc;
  for (int ci = 0; ci < nch; ++ci){
    int t0 = ci * Tc;
    hipLaunchKernelGGL(k_gproj, dim3((ZB * Tc / 64) * 8), dim3(256), 0, stream,
                       X1, Wc, bc, Gc, t0, lgTc);
    hipLaunchKernelGGL(k_lstm, dim3(ZB / 16), dim3(256), 0, stream,
                       Gc, Whh, Wfc, bfc, csv, hsv, out, Tc,
                       (ci == 0) ? 1 : 0, (ci == nch - 1) ? 1 : 0);
  }
}

// Round 2
// 7500.535 us; speedup vs baseline: 5.2967x; 5.2967x over previous
//
#include <hip/hip_runtime.h>
#include <cstdint>
#include <cstddef>

#define ZB 512
#define ZT 256
#define ZIN 64
#define ZEH 128
#define ZH 512
#define ZG 2048
#define ZNC 8
#define NBLK 256

typedef __attribute__((ext_vector_type(8))) short s8v;
typedef __attribute__((ext_vector_type(4))) float f4v;
typedef unsigned short u16;
typedef unsigned int u32;

__device__ __forceinline__ u16 f2bf(float f){
  u32 u = __builtin_bit_cast(u32, f);
  u += 0x7FFFu + ((u >> 16) & 1u);
  return (u16)(u >> 16);
}

// ---------------------------------------------------------------------------
// Fold: Wc[2048][128] = W_ih @ W2 (bf16), bc[2048] = W_ih@b2 + b_ih + b_hh
// ---------------------------------------------------------------------------
__global__ __launch_bounds__(128)
void k_fold(const float* __restrict__ W_ih, const float* __restrict__ W2,
            const float* __restrict__ b2, const float* __restrict__ b_ih,
            const float* __restrict__ b_hh, u16* __restrict__ Wc,
            float* __restrict__ bc)
{
  const int r = blockIdx.x, c = threadIdx.x;
  const float* wr = W_ih + (size_t)r * ZH;
  float acc = 0.f;
  for (int k = 0; k < ZH; ++k) acc += wr[k] * W2[(size_t)k * ZEH + c];
  Wc[(size_t)r * ZEH + c] = f2bf(acc);
  __shared__ float red[128];
  float p = 0.f;
  for (int k = c; k < ZH; k += 128) p += wr[k] * b2[k];
  red[c] = p; __syncthreads();
  for (int s = 64; s > 0; s >>= 1){ if (c < s) red[c] += red[c + s]; __syncthreads(); }
  if (c == 0) bc[r] = red[0] + b_ih[r] + b_hh[r];
}

// ---------------------------------------------------------------------------
// f32 -> bf16 cast
// ---------------------------------------------------------------------------
__global__ __launch_bounds__(256)
void k_cvt(const float* __restrict__ src, u16* __restrict__ dst, int n)
{
  int i = blockIdx.x * 256 + threadIdx.x;
  if (i < n) dst[i] = f2bf(src[i]);
}

// ---------------------------------------------------------------------------
// Encoder layer 1: X1[B*T][128] = bf16(LeakyReLU(seq @ W1^T + b1))
// ---------------------------------------------------------------------------
__global__ __launch_bounds__(256)
void k_enc(const float* __restrict__ seq, const float* __restrict__ W1,
           const float* __restrict__ b1, u16* __restrict__ X1)
{
  __shared__ float w1s[ZEH * 65];
  __shared__ float sqs[64 * 65];
  const int tid = threadIdx.x;
  const size_t rb = (size_t)blockIdx.x * 64;
  for (int i = tid; i < ZEH * ZIN; i += 256){ int r = i >> 6, c = i & 63; w1s[r * 65 + c] = W1[i]; }
  for (int i = tid; i < 64 * ZIN; i += 256){ int r = i >> 6, c = i & 63; sqs[r * 65 + c] = seq[(rb + r) * ZIN + c]; }
  __syncthreads();
  const int cg = tid & 31, rg = tid >> 5;
  float acc[8][4];
  #pragma unroll
  for (int i = 0; i < 8; ++i){
    #pragma unroll
    for (int j = 0; j < 4; ++j) acc[i][j] = 0.f;
  }
  for (int k = 0; k < ZIN; ++k){
    float wv[4], sv[8];
    #pragma unroll
    for (int j = 0; j < 4; ++j) wv[j] = w1s[(cg * 4 + j) * 65 + k];
    #pragma unroll
    for (int i = 0; i < 8; ++i) sv[i] = sqs[(rg * 8 + i) * 65 + k];
    #pragma unroll
    for (int i = 0; i < 8; ++i){
      #pragma unroll
      for (int j = 0; j < 4; ++j) acc[i][j] += sv[i] * wv[j];
    }
  }
  #pragma unroll
  for (int i = 0; i < 8; ++i){
    ushort4 pk;
    float v0 = acc[i][0] + b1[cg * 4 + 0]; v0 = v0 > 0.f ? v0 : 0.01f * v0;
    float v1 = acc[i][1] + b1[cg * 4 + 1]; v1 = v1 > 0.f ? v1 : 0.01f * v1;
    float v2 = acc[i][2] + b1[cg * 4 + 2]; v2 = v2 > 0.f ? v2 : 0.01f * v2;
    float v3 = acc[i][3] + b1[cg * 4 + 3]; v3 = v3 > 0.f ? v3 : 0.01f * v3;
    pk.x = f2bf(v0); pk.y = f2bf(v1); pk.z = f2bf(v2); pk.w = f2bf(v3);
    *(ushort4*)(X1 + (rb + rg * 8 + i) * ZEH + cg * 4) = pk;
  }
}

// ---------------------------------------------------------------------------
// Cooperative LSTM over all T=256 steps.
// 256 blocks = 8 batch-groups (64 rows) x 32 hcol-groups (16 h-cols).
// Wave w owns 16 gate rows: gate gt (lr>>2) x hcol jj (lr&3) interleave.
// W_hh slice + folded Wc slice live in registers for the whole kernel.
// h exchanged via double-buffered global hbuf + device-wide spin barrier.
// ---------------------------------------------------------------------------
__global__ __launch_bounds__(256, 2)
void k_lstm(const u16* __restrict__ X1, const u16* __restrict__ Whh,
            const u16* __restrict__ Wcf, const float* __restrict__ bc,
            const u16* __restrict__ Wfcb, const float* __restrict__ bfc,
            u16* __restrict__ hbuf, float* __restrict__ out,
            unsigned* __restrict__ cnt)
{
  __shared__ u16 hs[64 * ZH];   // 64 KiB, XOR-swizzled h tile
  const int tid = threadIdx.x;
  const int w = tid >> 6, l = tid & 63;
  const int lr = l & 15, lg = l >> 4;
  const int bg = (int)blockIdx.x >> 5, hg = (int)blockIdx.x & 31;
  const int gt = lr >> 2;
  const int grow = gt * ZH + hg * 16 + w * 4 + (lr & 3);  // gate row in [0,2048)

  // persistent B-operand fragments (W_hh slice: 64 VGPR, Wc slice: 16 VGPR)
  s8v bwh[16], bwx[4];
  {
    const u16* p = Whh + (size_t)grow * ZH + lg * 8;
    #pragma unroll
    for (int kt = 0; kt < 16; ++kt) bwh[kt] = *(const s8v*)(p + kt * 32);
    const u16* q = Wcf + (size_t)grow * ZEH + lg * 8;
    #pragma unroll
    for (int kt = 0; kt < 4; ++kt) bwx[kt] = *(const s8v*)(q + kt * 32);
  }
  const float bias = bc[grow];

  float c_reg[4][4];
  #pragma unroll
  for (int a = 0; a < 4; ++a){
    #pragma unroll
    for (int b = 0; b < 4; ++b) c_reg[a][b] = 0.f;
  }

  const u16* xbase[4];
  #pragma unroll
  for (int mt = 0; mt < 4; ++mt)
    xbase[mt] = X1 + (size_t)(bg * 64 + mt * 16 + lr) * (ZT * ZEH) + lg * 8;

  const int hcb = hg * 16 + w * 4;

  for (int t = 0; t < ZT; ++t){
    // stage h_{t-1} tile [64][512] bf16 into swizzled LDS (coalesced 16B)
    const u16* hsrc = hbuf + (size_t)(t & 1) * (ZB * ZH) + (size_t)bg * 64 * ZH;
    #pragma unroll
    for (int i = 0; i < 16; ++i){
      int c = tid + i * 256;        // 16B chunk; one wave instr = one row
      int byte = c * 16;
      int row = byte >> 10;
      s8v v = *(const s8v*)(hsrc + (size_t)c * 8);
      *(s8v*)((char*)hs + (byte ^ ((row & 7) << 4))) = v;
    }
    __syncthreads();

    u16* hdst = hbuf + (size_t)((t + 1) & 1) * (ZB * ZH);
    #pragma unroll
    for (int mt = 0; mt < 4; ++mt){
      f4v acc = {bias, bias, bias, bias};
      const u16* xp = xbase[mt] + (size_t)t * ZEH;
      s8v ax0 = *(const s8v*)(xp);
      s8v ax1 = *(const s8v*)(xp + 32);
      s8v ax2 = *(const s8v*)(xp + 64);
      s8v ax3 = *(const s8v*)(xp + 96);
      #pragma unroll
      for (int kt = 0; kt < 16; ++kt){
        int row = mt * 16 + lr;
        int byte = row * (ZH * 2) + kt * 64 + lg * 16;
        s8v av = *(const s8v*)((char*)hs + (byte ^ ((row & 7) << 4)));
        acc = __builtin_amdgcn_mfma_f32_16x16x32_bf16(av, bwh[kt], acc, 0, 0, 0);
      }
      acc = __builtin_amdgcn_mfma_f32_16x16x32_bf16(ax0, bwx[0], acc, 0, 0, 0);
      acc = __builtin_amdgcn_mfma_f32_16x16x32_bf16(ax1, bwx[1], acc, 0, 0, 0);
      acc = __builtin_amdgcn_mfma_f32_16x16x32_bf16(ax2, bwx[2], acc, 0, 0, 0);
      acc = __builtin_amdgcn_mfma_f32_16x16x32_bf16(ax3, bwx[3], acc, 0, 0, 0);

      // LSTM cell: lanes lr<4 (i-gate lanes) gather f,g,o via shfl_xor
      #pragma unroll
      for (int r = 0; r < 4; ++r){
        float v = acc[r];
        float s = (gt == 2) ? 2.f : -1.f;
        float e = __expf(v * s);
        float rc = 1.f / (1.f + e);
        float a = (gt == 2) ? (1.f - 2.f * rc) : rc;   // tanh : sigmoid
        float f_ = __shfl_xor(a, 4);
        float g_ = __shfl_xor(a, 8);
        float o_ = __shfl_xor(a, 12);
        float cv = f_ * c_reg[mt][r] + a * g_;
        c_reg[mt][r] = cv;
        float e2 = __expf(2.f * cv);
        float hv = o_ * (1.f - 2.f / (1.f + e2));
        u32 bits = f2bf(hv);
        u32 lo = bits | (((u32)__shfl_xor((int)bits, 1)) << 16);
        u32 hi = (u32)__shfl_xor((int)lo, 2);
        if (lr == 0){
          int rrow = bg * 64 + mt * 16 + lg * 4 + r;
          uint2 pk; pk.x = lo; pk.y = hi;
          *(uint2*)(hdst + (size_t)rrow * ZH + hcb) = pk;   // 4 h-cols, 8B
        }
      }
    }

    // device-wide barrier (monotonic counter; reset by hipMemsetAsync host-side)
    __syncthreads();
    if (tid == 0){
      __threadfence();   // release: flush h stores to coherence point
      __hip_atomic_fetch_add(cnt, 1u, __ATOMIC_RELAXED, __HIP_MEMORY_SCOPE_AGENT);
      if (t < ZT - 1 || hg == 0){
        unsigned tgt = (unsigned)(t + 1) * NBLK;
        long long guard = 0;
        while (__hip_atomic_load(cnt, __ATOMIC_RELAXED, __HIP_MEMORY_SCOPE_AGENT) < tgt){
          __builtin_amdgcn_s_sleep(2);
          if (++guard > 100000000LL) break;   // fail loud (wrong answer), not hang
        }
        __threadfence();  // acquire: invalidate L1/L2 before reading fresh h
      }
    }
    __syncthreads();
  }

  // epilogue: hg==0 blocks compute out = h_T @ Wfc^T + bfc  (h_T is in hbuf[0])
  if (hg == 0){
    float ob = (lr < ZNC) ? bfc[lr] : 0.f;
    f4v acc = {ob, ob, ob, ob};
    const u16* hp = hbuf + (size_t)(bg * 64 + w * 16 + lr) * ZH + lg * 8;
    const u16* wp = Wfcb + (size_t)lr * ZH + lg * 8;
    #pragma unroll
    for (int kt = 0; kt < 16; ++kt){
      s8v av = *(const s8v*)(hp + kt * 32);
      s8v bv = *(const s8v*)(wp + kt * 32);
      acc = __builtin_amdgcn_mfma_f32_16x16x32_bf16(av, bv, acc, 0, 0, 0);
    }
    if (lr < ZNC){
      #pragma unroll
      for (int r = 0; r < 4; ++r)
        out[(size_t)(bg * 64 + w * 16 + lg * 4 + r) * ZNC + lr] = acc[r];
    }
  }
}

// ---------------------------------------------------------------------------
extern "C" void kernel_launch(void* const* d_in, const int* in_sizes, int n_in,
                              void* d_out, int out_size, void* d_ws, size_t ws_size,
                              hipStream_t stream)
{
  const float* seq  = (const float*)d_in[0];
  const float* W1   = (const float*)d_in[1];
  const float* b1   = (const float*)d_in[2];
  const float* W2   = (const float*)d_in[3];
  const float* b2   = (const float*)d_in[4];
  const float* W_ih = (const float*)d_in[5];
  const float* W_hh = (const float*)d_in[6];
  const float* b_ih = (const float*)d_in[7];
  const float* b_hh = (const float*)d_in[8];
  const float* Wfc  = (const float*)d_in[9];
  const float* bfc  = (const float*)d_in[10];
  float* out = (float*)d_out;

  char* ws = (char*)d_ws;
  size_t off = 0;
  auto alloc = [&](size_t bytes){ void* p = ws + off; off += (bytes + 255) & ~(size_t)255; return p; };
  u16*      Wc   = (u16*)     alloc((size_t)ZG * ZEH * 2);
  float*    bc   = (float*)   alloc((size_t)ZG * 4);
  u16*      Whh  = (u16*)     alloc((size_t)ZG * ZH * 2);
  u16*      Wfcb = (u16*)     alloc((size_t)16 * ZH * 2);
  u16*      X1   = (u16*)     alloc((size_t)ZB * ZT * ZEH * 2);
  u16*      hbuf = (u16*)     alloc((size_t)2 * ZB * ZH * 2);
  unsigned* cnt  = (unsigned*)alloc(256);

  hipMemsetAsync(cnt, 0, 256, stream);
  hipMemsetAsync(hbuf, 0, (size_t)ZB * ZH * 2, stream);      // h_0 = 0 (buffer 0)
  hipMemsetAsync(Wfcb, 0, (size_t)16 * ZH * 2, stream);      // pad rows 8..15 = 0

  hipLaunchKernelGGL(k_fold, dim3(ZG), dim3(128), 0, stream, W_ih, W2, b2, b_ih, b_hh, Wc, bc);
  hipLaunchKernelGGL(k_cvt, dim3((ZG * ZH + 255) / 256), dim3(256), 0, stream, W_hh, Whh, ZG * ZH);
  hipLaunchKernelGGL(k_cvt, dim3((ZNC * ZH + 255) / 256), dim3(256), 0, stream, Wfc, Wfcb, ZNC * ZH);
  hipLaunchKernelGGL(k_enc, dim3(ZB * ZT / 64), dim3(256), 0, stream, seq, W1, b1, X1);
  hipLaunchKernelGGL(k_lstm, dim3(NBLK), dim3(256), 0, stream,
                     X1, Whh, Wc, bc, Wfcb, bfc, hbuf, out, cnt);
}